// Round 8
// baseline (66.216 us; speedup 1.0000x reference)
//
#include <hip/hip_runtime.h>

// VA forward: out[row, 3j:3j+3] = M(theta_row) @ ((p + t) * (p != 0))
// where M = Rz(th2) * Ry(th0) * Rx(th1), t = th[3:6].
// One thread per joint (best structure, R7 = 64.9us).
// This round's isolated change: the 3 NT scalar loads -> ONE overlapping
// 16B NT load (lane reads [12l,12l+16), uses first 12B). Each wave-level
// load instruction now touches every cacheline exactly once, removing any
// cross-instruction NT (no-allocate) re-fetch risk. Stores stay cached
// scalars (R7-proven: L2 write-combines, no amplification).

constexpr int JOINTS = 25;

typedef float f32x4a __attribute__((ext_vector_type(4), aligned(4)));

__global__ __launch_bounds__(256) void va_kernel(
    const float* __restrict__ conv,
    const float* __restrict__ theta,
    float* __restrict__ out,
    int total)   // total = N * JOINTS joint-tasks
{
    int idx = blockIdx.x * 256 + threadIdx.x;
    if (idx >= total) return;

    unsigned row = (unsigned)idx / JOINTS;        // magic-mul div by 25
    unsigned j   = (unsigned)idx - row * JOINTS;

    // ---- one 16B NT load, first 12B used (4B overlap with neighbor) ----
    const float* p = conv + (size_t)row * 75 + j * 3;
    f32x4a A = __builtin_nontemporal_load((const f32x4a*)p);
    float x = A.x, y = A.y, z = A.z;

    const float* th = theta + (size_t)row * 6;
    float ay = th[0], ax = th[1], az = th[2];
    float tx = th[3], ty = th[4], tz = th[5];

    float sy = __sinf(ay), cy = __cosf(ay);
    float sx = __sinf(ax), cx = __cosf(ax);
    float sz = __sinf(az), cz = __cosf(az);

    // M = Rz(az) * Ry(ay) * Rx(ax)
    float m00 = cz * cy;
    float m01 = -sz * cx + cz * sy * sx;
    float m02 =  sz * sx + cz * sy * cx;
    float m10 = sz * cy;
    float m11 =  cz * cx + sz * sy * sx;
    float m12 = -cz * sx + sz * sy * cx;
    float m20 = -sy;
    float m21 = cy * sx;
    float m22 = cy * cx;

    float qx = (x != 0.0f) ? (x + tx) : 0.0f;
    float qy = (y != 0.0f) ? (y + ty) : 0.0f;
    float qz = (z != 0.0f) ? (z + tz) : 0.0f;

    float ox = m00 * qx + m01 * qy + m02 * qz;
    float oy = m10 * qx + m11 * qy + m12 * qz;
    float oz = m20 * qx + m21 * qy + m22 * qz;

    float* o = out + (size_t)row * 75 + j * 3;
    o[0] = ox;   // cached stores: L2 write-combines stride-12 scalars
    o[1] = oy;
    o[2] = oz;
}

extern "C" void kernel_launch(void* const* d_in, const int* in_sizes, int n_in,
                              void* d_out, int out_size, void* d_ws, size_t ws_size,
                              hipStream_t stream) {
    const float* conv  = (const float*)d_in[0];
    const float* theta = (const float*)d_in[1];
    float* out = (float*)d_out;

    int total = out_size / 3;                 // N * 25 joint tasks
    int blocks = (total + 255) / 256;         // 60,000 exact
    va_kernel<<<blocks, 256, 0, stream>>>(conv, theta, out, total);
}

// Round 9
// 65.373 us; speedup vs baseline: 1.0129x; 1.0129x over previous
//
#include <hip/hip_runtime.h>

// VA forward: out[row, 3j:3j+3] = M(theta_row) @ ((p + t) * (p != 0))
// where M = Rz(th2) * Ry(th0) * Rx(th1), t = th[3:6].
//
// FINAL (R7 structure, best = 64.9us = 5.9 TB/s effective, ~94% of the
// 6.29 TB/s measured mixed-stream ceiling):
//  - one thread per joint; wave accesses are dense 768B groups
//  - NT (no-allocate) LOADS on the read-once conv stream
//  - CACHED scalar stores: L2 write-combines stride-12 scalars into full
//    lines (NT stores caused +40% WRITE_SIZE amplification, R5)
//  - theta loads cached (25x reuse per row, L1 broadcast)
// Rejected by experiment: LDS staging (R2/R3: +4-7us overhead), 5-joint
// batching (R5: partial-line NT stores), dense-float4+shuffle (R6: VALU
// storm), overlapping 16B NT load (R8: +1.3us).

constexpr int JOINTS = 25;

__global__ __launch_bounds__(256) void va_kernel(
    const float* __restrict__ conv,
    const float* __restrict__ theta,
    float* __restrict__ out,
    int total)   // total = N * JOINTS joint-tasks
{
    int idx = blockIdx.x * 256 + threadIdx.x;
    if (idx >= total) return;

    unsigned row = (unsigned)idx / JOINTS;        // magic-mul div by 25
    unsigned j   = (unsigned)idx - row * JOINTS;

    const float* th = theta + (size_t)row * 6;
    float ay = th[0], ax = th[1], az = th[2];
    float tx = th[3], ty = th[4], tz = th[5];

    float sy = __sinf(ay), cy = __cosf(ay);
    float sx = __sinf(ax), cx = __cosf(ax);
    float sz = __sinf(az), cz = __cosf(az);

    // M = Rz(az) * Ry(ay) * Rx(ax)
    float m00 = cz * cy;
    float m01 = -sz * cx + cz * sy * sx;
    float m02 =  sz * sx + cz * sy * cx;
    float m10 = sz * cy;
    float m11 =  cz * cx + sz * sy * sx;
    float m12 = -cz * sx + sz * sy * cx;
    float m20 = -sy;
    float m21 = cy * sx;
    float m22 = cy * cx;

    const float* p = conv + (size_t)row * 75 + j * 3;
    float x = __builtin_nontemporal_load(p + 0);
    float y = __builtin_nontemporal_load(p + 1);
    float z = __builtin_nontemporal_load(p + 2);

    float qx = (x != 0.0f) ? (x + tx) : 0.0f;
    float qy = (y != 0.0f) ? (y + ty) : 0.0f;
    float qz = (z != 0.0f) ? (z + tz) : 0.0f;

    float ox = m00 * qx + m01 * qy + m02 * qz;
    float oy = m10 * qx + m11 * qy + m12 * qz;
    float oz = m20 * qx + m21 * qy + m22 * qz;

    float* o = out + (size_t)row * 75 + j * 3;
    o[0] = ox;   // cached stores: L2 write-combines stride-12 scalars
    o[1] = oy;
    o[2] = oz;
}

extern "C" void kernel_launch(void* const* d_in, const int* in_sizes, int n_in,
                              void* d_out, int out_size, void* d_ws, size_t ws_size,
                              hipStream_t stream) {
    const float* conv  = (const float*)d_in[0];
    const float* theta = (const float*)d_in[1];
    float* out = (float*)d_out;

    int total = out_size / 3;                 // N * 25 joint tasks
    int blocks = (total + 255) / 256;         // 60,000 exact
    va_kernel<<<blocks, 256, 0, stream>>>(conv, theta, out, total);
}